// Round 13
// baseline (871.308 us; speedup 1.0000x reference)
//
#include <hip/hip_runtime.h>
#include <math.h>

#define BB 32
#define PP 64
#define SS 128
#define DD 768
#define HH 8
#define HD 96
#define EE 8
#define LL 4
#define NTOK 4096
#define NASSIGN 8192
#define QKVN 2304

typedef __attribute__((ext_vector_type(8))) short bf16x8;
typedef __attribute__((ext_vector_type(4))) float f32x4;

__device__ __forceinline__ float bf2f(unsigned short u) {
  union { unsigned int i; float f; } v; v.i = ((unsigned int)u) << 16; return v.f;
}
__device__ __forceinline__ unsigned short f2bf(float f) {
  union { float f; unsigned int u; } v; v.f = f;
  unsigned int r = v.u + 0x7FFFu + ((v.u >> 16) & 1u);
  return (unsigned short)(r >> 16);
}
__device__ __forceinline__ void gload16(const void* g, void* l) {
  __builtin_amdgcn_global_load_lds((const __attribute__((address_space(1))) unsigned int*)g,
                                   (__attribute__((address_space(3))) unsigned int*)l, 16, 0, 0);
}

// ---------------- weight transpose + bf16 convert: W[K][N] f32 -> WT[N][K] bf16 ----------------
__global__ __launch_bounds__(256) void tconv_k(const float* __restrict__ W, unsigned short* __restrict__ WT,
                                               int K, int N) {
  const float* Wb = W + (size_t)blockIdx.z * K * N;
  unsigned short* WTb = WT + (size_t)blockIdx.z * K * N;
  __shared__ float t[32][33];
  int tx = threadIdx.x & 31, ty = threadIdx.x >> 5;
  int n0 = blockIdx.x * 32, k0 = blockIdx.y * 32;
#pragma unroll
  for (int r = 0; r < 4; ++r) t[ty * 4 + r][tx] = Wb[(size_t)(k0 + ty * 4 + r) * N + n0 + tx];
  __syncthreads();
#pragma unroll
  for (int r = 0; r < 4; ++r) WTb[(size_t)(n0 + ty * 4 + r) * K + k0 + tx] = f2bf(t[tx][ty * 4 + r]);
}

// ---------------- LayerNorm: X f32 -> (Y f32 optional) + Yb bf16 ----------------
template <bool WRITEY>
__global__ __launch_bounds__(256) void ln_k(const float* __restrict__ X, float* __restrict__ Y,
                                            unsigned short* __restrict__ Yb,
                                            const float* __restrict__ w, const float* __restrict__ b) {
  int r = blockIdx.x; int tid = threadIdx.x;
  const float* x = X + (size_t)r * DD;
  float v0 = x[tid], v1 = x[tid + 256], v2 = x[tid + 512];
  __shared__ float rs[256], rss[256];
  rs[tid] = v0 + v1 + v2;
  rss[tid] = v0 * v0 + v1 * v1 + v2 * v2;
  __syncthreads();
  for (int off = 128; off > 0; off >>= 1) {
    if (tid < off) { rs[tid] += rs[tid + off]; rss[tid] += rss[tid + off]; }
    __syncthreads();
  }
  float mean = rs[0] * (1.f / DD);
  float var = rss[0] * (1.f / DD) - mean * mean;
  float rstd = rsqrtf(var + 1e-5f);
  unsigned short* yb = Yb + (size_t)r * DD;
  float o0 = (v0 - mean) * rstd * w[tid] + b[tid];
  float o1 = (v1 - mean) * rstd * w[tid + 256] + b[tid + 256];
  float o2 = (v2 - mean) * rstd * w[tid + 512] + b[tid + 512];
  if (WRITEY) {
    float* y = Y + (size_t)r * DD;
    y[tid] = o0; y[tid + 256] = o1; y[tid + 512] = o2;
  }
  yb[tid] = f2bf(o0); yb[tid + 256] = f2bf(o1); yb[tid + 512] = f2bf(o2);
}

// ---------------- MFMA GEMM, 64x128 tile, BK=64, swizzled LDS, XCD M-affinity remap ----------------
// 1D grid of (M/64)*(N/128) blocks; M/64 must be divisible by 8.
// EPI 1: f32 2*(v+bias)   2: bf16 gelu(v+bias)   3: f32 res+v+bias   5: bf16 v
template <int EPI>
__global__ __launch_bounds__(256) void mgemm_k(const unsigned short* __restrict__ A,
                                               const unsigned short* __restrict__ WT,
                                               const float* __restrict__ bias, void* __restrict__ Cv,
                                               const float* res, int M, int N, int K) {
  __shared__ short As[64 * 64];
  __shared__ short Bs[128 * 64];
  int tid = threadIdx.x;
  int wv = tid >> 6, ln = tid & 63;
  int NT = N >> 7;
  int bid = blockIdx.x;
  int xcd = bid & 7, k = bid >> 3;
  int m0 = ((k / NT) * 8 + xcd) * 64;
  int n0 = (k % NT) * 128;
  f32x4 acc[2][4] = {};
  int lr = ln & 15, kc = ln >> 4;
  int wr = wv >> 1, wc = wv & 1;
  int srow = ln >> 3;
  int scol = ((ln & 7) ^ srow) * 8;
  for (int k0 = 0; k0 < K; k0 += 64) {
#pragma unroll
    for (int i = 0; i < 2; ++i) {
      int ch = wv * 2 + i;
      gload16(A + (size_t)(m0 + ch * 8 + srow) * K + k0 + scol, &As[ch * 512]);
    }
#pragma unroll
    for (int c = 0; c < 4; ++c) {
      int ch = wv * 4 + c;
      gload16(WT + (size_t)(n0 + ch * 8 + srow) * K + k0 + scol, &Bs[ch * 512]);
    }
    __syncthreads();
#pragma unroll
    for (int ks = 0; ks < 2; ++ks) {
      int sl = ((ks * 4 + kc) ^ (lr & 7)) * 8;
      bf16x8 af[2], bfr[4];
#pragma unroll
      for (int i = 0; i < 2; ++i) af[i] = *(const bf16x8*)&As[(wr * 32 + i * 16 + lr) * 64 + sl];
#pragma unroll
      for (int j = 0; j < 4; ++j) bfr[j] = *(const bf16x8*)&Bs[(wc * 64 + j * 16 + lr) * 64 + sl];
#pragma unroll
      for (int i = 0; i < 2; ++i)
#pragma unroll
        for (int j = 0; j < 4; ++j)
          acc[i][j] = __builtin_amdgcn_mfma_f32_16x16x32_bf16(af[i], bfr[j], acc[i][j], 0, 0, 0);
    }
    __syncthreads();
  }
  int lg = ln >> 4;
#pragma unroll
  for (int i = 0; i < 2; ++i)
#pragma unroll
    for (int j = 0; j < 4; ++j)
#pragma unroll
      for (int r = 0; r < 4; ++r) {
        int m = m0 + wr * 32 + i * 16 + lg * 4 + r;
        int n = n0 + wc * 64 + j * 16 + lr;
        float v = acc[i][j][r];
        if constexpr (EPI == 1) { ((float*)Cv)[(size_t)m * N + n] = 2.f * (v + bias[n]); }
        else if constexpr (EPI == 2) { v += bias[n]; v = 0.5f * v * (1.f + erff(v * 0.70710678118f)); ((unsigned short*)Cv)[(size_t)m * N + n] = f2bf(v); }
        else if constexpr (EPI == 3) { ((float*)Cv)[(size_t)m * N + n] = res[(size_t)m * N + n] + v + bias[n]; }
        else { ((unsigned short*)Cv)[(size_t)m * N + n] = f2bf(v); }
      }
}

// ---------------- expert up-proj GEMM, 64x256 tile, fused gather via tokmap ----------------
// grid = (N/256, 128 slots, 8 experts); A rows loaded directly from Yb[tokmap[slot]].
// EPI 2: bf16 gelu(v+bias)
__global__ __launch_bounds__(256) void megemmA_k(const unsigned short* __restrict__ Yb,
                                                 const int* __restrict__ tokmap,
                                                 const unsigned short* __restrict__ WTall,
                                                 const float* __restrict__ Ball, unsigned short* __restrict__ C,
                                                 const int* __restrict__ offs, const int* __restrict__ cntp,
                                                 int N, int K) {
  int e = blockIdx.z;
  int cnt = cntp[e];
  int mt = blockIdx.y;
  if (mt * 64 >= cnt) return;
  int valid = cnt - mt * 64; if (valid > 64) valid = 64;
  int base = offs[e] + mt * 64;
  const unsigned short* WT = WTall + (size_t)e * K * N;
  const float* Bv = Ball + (size_t)e * N;
  unsigned short* Ce = C + (size_t)base * N;
  __shared__ short As[64 * 64];
  __shared__ short Bs[256 * 64];
  int tid = threadIdx.x;
  int wv = tid >> 6, ln = tid & 63;
  int n0 = blockIdx.x * 256;
  f32x4 acc[2][8] = {};
  int lr = ln & 15, kc = ln >> 4;
  int wr = wv >> 1, wc = wv & 1;
  int srow = ln >> 3;
  int scol = ((ln & 7) ^ srow) * 8;
  int rowIdx[2];
#pragma unroll
  for (int i = 0; i < 2; ++i) {
    int gs = base + (wv * 2 + i) * 8 + srow;
    if (gs > NASSIGN - 1) gs = NASSIGN - 1;
    rowIdx[i] = tokmap[gs];
  }
  for (int k0 = 0; k0 < K; k0 += 64) {
#pragma unroll
    for (int i = 0; i < 2; ++i) {
      int ch = wv * 2 + i;
      gload16(Yb + (size_t)rowIdx[i] * DD + k0 + scol, &As[ch * 512]);
    }
#pragma unroll
    for (int c = 0; c < 8; ++c) {
      int ch = wv * 8 + c;
      gload16(WT + (size_t)(n0 + ch * 8 + srow) * K + k0 + scol, &Bs[ch * 512]);
    }
    __syncthreads();
#pragma unroll
    for (int ks = 0; ks < 2; ++ks) {
      int sl = ((ks * 4 + kc) ^ (lr & 7)) * 8;
      bf16x8 af[2], bfr[8];
#pragma unroll
      for (int i = 0; i < 2; ++i) af[i] = *(const bf16x8*)&As[(wr * 32 + i * 16 + lr) * 64 + sl];
#pragma unroll
      for (int j = 0; j < 8; ++j) bfr[j] = *(const bf16x8*)&Bs[(wc * 128 + j * 16 + lr) * 64 + sl];
#pragma unroll
      for (int i = 0; i < 2; ++i)
#pragma unroll
        for (int j = 0; j < 8; ++j)
          acc[i][j] = __builtin_amdgcn_mfma_f32_16x16x32_bf16(af[i], bfr[j], acc[i][j], 0, 0, 0);
    }
    __syncthreads();
  }
  int lg = ln >> 4;
#pragma unroll
  for (int i = 0; i < 2; ++i)
#pragma unroll
    for (int j = 0; j < 8; ++j)
#pragma unroll
      for (int r = 0; r < 4; ++r) {
        int ml = wr * 32 + i * 16 + lg * 4 + r;
        if (ml >= valid) continue;
        int n = n0 + wc * 128 + j * 16 + lr;
        float v = acc[i][j][r] + Bv[n];
        v = 0.5f * v * (1.f + erff(v * 0.70710678118f));
        Ce[(size_t)ml * N + n] = f2bf(v);
      }
}

// ---------------- grouped expert MFMA GEMM, 64x128 tile (r8 form: plain 3D grid, early exit) ----------------
// EPI 4: bf16 v+bias
template <int EPI>
__global__ __launch_bounds__(256) void megemm_k(const unsigned short* __restrict__ Aall,
                                                const unsigned short* __restrict__ WTall,
                                                const float* __restrict__ Ball, unsigned short* __restrict__ C,
                                                const int* __restrict__ offs, const int* __restrict__ cntp,
                                                int N, int K) {
  int e = blockIdx.z;
  int cnt = cntp[e];
  int mt = blockIdx.y;
  if (mt * 64 >= cnt) return;
  int valid = cnt - mt * 64; if (valid > 64) valid = 64;
  const unsigned short* A = Aall + (size_t)(offs[e] + mt * 64) * K;
  const unsigned short* WT = WTall + (size_t)e * K * N;
  const float* Bv = Ball + (size_t)e * N;
  unsigned short* Ce = C + (size_t)(offs[e] + mt * 64) * N;
  __shared__ short As[64 * 64];
  __shared__ short Bs[128 * 64];
  int tid = threadIdx.x;
  int wv = tid >> 6, ln = tid & 63;
  int n0 = blockIdx.x * 128;
  f32x4 acc[2][4] = {};
  int lr = ln & 15, kc = ln >> 4;
  int wr = wv >> 1, wc = wv & 1;
  int srow = ln >> 3;
  int scol = ((ln & 7) ^ srow) * 8;
  for (int k0 = 0; k0 < K; k0 += 64) {
#pragma unroll
    for (int i = 0; i < 2; ++i) {
      int ch = wv * 2 + i;
      gload16(A + (size_t)(ch * 8 + srow) * K + k0 + scol, &As[ch * 512]);
    }
#pragma unroll
    for (int c = 0; c < 4; ++c) {
      int ch = wv * 4 + c;
      gload16(WT + (size_t)(n0 + ch * 8 + srow) * K + k0 + scol, &Bs[ch * 512]);
    }
    __syncthreads();
#pragma unroll
    for (int ks = 0; ks < 2; ++ks) {
      int sl = ((ks * 4 + kc) ^ (lr & 7)) * 8;
      bf16x8 af[2], bfr[4];
#pragma unroll
      for (int i = 0; i < 2; ++i) af[i] = *(const bf16x8*)&As[(wr * 32 + i * 16 + lr) * 64 + sl];
#pragma unroll
      for (int j = 0; j < 4; ++j) bfr[j] = *(const bf16x8*)&Bs[(wc * 64 + j * 16 + lr) * 64 + sl];
#pragma unroll
      for (int i = 0; i < 2; ++i)
#pragma unroll
        for (int j = 0; j < 4; ++j)
          acc[i][j] = __builtin_amdgcn_mfma_f32_16x16x32_bf16(af[i], bfr[j], acc[i][j], 0, 0, 0);
    }
    __syncthreads();
  }
  int lg = ln >> 4;
#pragma unroll
  for (int i = 0; i < 2; ++i)
#pragma unroll
    for (int j = 0; j < 4; ++j)
#pragma unroll
      for (int r = 0; r < 4; ++r) {
        int ml = wr * 32 + i * 16 + lg * 4 + r;
        if (ml >= valid) continue;
        int n = n0 + wc * 64 + j * 16 + lr;
        float v = acc[i][j][r] + Bv[n];
        if constexpr (EPI == 2) { v = 0.5f * v * (1.f + erff(v * 0.70710678118f)); }
        Ce[(size_t)ml * N + n] = f2bf(v);
      }
}

// ---------------- fused attention: one WG per (b,h), reads combined QKV (stride 2304) ----------------
__global__ __launch_bounds__(256) void attn_fused_k(const unsigned short* __restrict__ QKV,
                                                    unsigned short* __restrict__ AOb) {
  __shared__ short lds[57088];
  const int QS = 0, KS = 13312, VT = 26624, PS = 39680;
  int tid = threadIdx.x;
  int b = blockIdx.x >> 3, h = blockIdx.x & 7;
  const size_t qbase = (size_t)(b * SS) * QKVN + h * HD;
  for (int c = tid; c < 1536; c += 256) {
    int row = c / 12, col8 = c % 12;
    uint4 v = *(const uint4*)(QKV + qbase + (size_t)row * QKVN + col8 * 8);
    *(uint4*)&lds[QS + row * 104 + col8 * 8] = v;
  }
  const size_t kbase = qbase + DD;
  for (int c = tid; c < 1536; c += 256) {
    int row = c / 12, col8 = c % 12;
    uint4 v = *(const uint4*)(QKV + kbase + (size_t)row * QKVN + col8 * 8);
    *(uint4*)&lds[KS + row * 104 + col8 * 8] = v;
  }
  const size_t vbase = qbase + 2 * DD;
  for (int c = tid; c < 6144; c += 256) {
    int j = c / 48, dp = c % 48;
    unsigned int u = *(const unsigned int*)(QKV + vbase + (size_t)j * QKVN + dp * 2);
    lds[VT + (2 * dp) * 136 + j] = (short)(u & 0xFFFF);
    lds[VT + (2 * dp + 1) * 136 + j] = (short)(u >> 16);
  }
  __syncthreads();

  int w = tid >> 6, ln = tid & 63;
  int lr = ln & 15, kc = ln >> 4;
  f32x4 acc[2][8] = {};
#pragma unroll
  for (int kk = 0; kk < 3; ++kk) {
    bf16x8 af[2], bfv[8];
#pragma unroll
    for (int i = 0; i < 2; ++i)
      af[i] = *(const bf16x8*)&lds[QS + (32 * w + i * 16 + lr) * 104 + kk * 32 + kc * 8];
#pragma unroll
    for (int j = 0; j < 8; ++j)
      bfv[j] = *(const bf16x8*)&lds[KS + (j * 16 + lr) * 104 + kk * 32 + kc * 8];
#pragma unroll
    for (int i = 0; i < 2; ++i)
#pragma unroll
      for (int j = 0; j < 8; ++j)
        acc[i][j] = __builtin_amdgcn_mfma_f32_16x16x32_bf16(af[i], bfv[j], acc[i][j], 0, 0, 0);
  }
  const float c1 = 0.10206207261596577f * 1.4426950408889634f;
  float inv_[2][4];
#pragma unroll
  for (int i = 0; i < 2; ++i)
#pragma unroll
    for (int r = 0; r < 4; ++r) {
      float m = acc[i][0][r];
#pragma unroll
      for (int j = 1; j < 8; ++j) m = fmaxf(m, acc[i][j][r]);
      m = fmaxf(m, __shfl_xor(m, 1, 64)); m = fmaxf(m, __shfl_xor(m, 2, 64));
      m = fmaxf(m, __shfl_xor(m, 4, 64)); m = fmaxf(m, __shfl_xor(m, 8, 64));
      float p[8]; float s = 0.f;
#pragma unroll
      for (int j = 0; j < 8; ++j) { p[j] = exp2f((acc[i][j][r] - m) * c1); s += p[j]; }
      s += __shfl_xor(s, 1, 64); s += __shfl_xor(s, 2, 64);
      s += __shfl_xor(s, 4, 64); s += __shfl_xor(s, 8, 64);
      inv_[i][r] = 1.f / s;
      short* pw = &lds[PS + w * 4352 + (i * 16 + kc * 4 + r) * 136 + lr];
#pragma unroll
      for (int j = 0; j < 8; ++j) pw[j * 16] = (short)f2bf(p[j]);
    }
  f32x4 acc2[2][6] = {};
#pragma unroll
  for (int kk = 0; kk < 4; ++kk) {
    bf16x8 pa[2], vb[6];
#pragma unroll
    for (int i = 0; i < 2; ++i)
      pa[i] = *(const bf16x8*)&lds[PS + w * 4352 + (i * 16 + lr) * 136 + kk * 32 + kc * 8];
#pragma unroll
    for (int j = 0; j < 6; ++j)
      vb[j] = *(const bf16x8*)&lds[VT + (j * 16 + lr) * 136 + kk * 32 + kc * 8];
#pragma unroll
    for (int i = 0; i < 2; ++i)
#pragma unroll
      for (int j = 0; j < 6; ++j)
        acc2[i][j] = __builtin_amdgcn_mfma_f32_16x16x32_bf16(pa[i], vb[j], acc2[i][j], 0, 0, 0);
  }
#pragma unroll
  for (int i = 0; i < 2; ++i)
#pragma unroll
    for (int j = 0; j < 6; ++j)
#pragma unroll
      for (int r = 0; r < 4; ++r) {
        int row = 32 * w + i * 16 + kc * 4 + r;
        AOb[((size_t)b * SS + row) * DD + h * HD + j * 16 + lr] = f2bf(acc2[i][j][r] * inv_[i][r]);
      }
}

// ---------------- MoE gating ----------------
__global__ __launch_bounds__(256) void gate_logits_k(const float* __restrict__ Y, const float* __restrict__ wg,
                                                     float* __restrict__ logits) {
  int t = blockIdx.x; int tid = threadIdx.x;
  int e = tid >> 5, lane = tid & 31;
  const float* y = Y + (size_t)t * DD;
  float s = 0.f;
  for (int d = lane; d < DD; d += 32) s = fmaf(y[d], wg[(size_t)d * EE + e], s);
  for (int off = 16; off > 0; off >>= 1) s += __shfl_down(s, off, 32);
  if (lane == 0) logits[(size_t)t * EE + e] = s;
}

__global__ __launch_bounds__(256) void topk_k(const float* __restrict__ logits, int* __restrict__ te,
                                              float* __restrict__ tg, int* __restrict__ cnt) {
  __shared__ int lcnt[EE];
  if (threadIdx.x < EE) lcnt[threadIdx.x] = 0;
  __syncthreads();
  int t = blockIdx.x * 256 + threadIdx.x;
  if (t < NTOK) {
    const float* l = logits + (size_t)t * EE;
    int i1 = 0; float v1 = l[0];
    for (int e = 1; e < EE; ++e) { float v = l[e]; if (v > v1) { v1 = v; i1 = e; } }
    int i2 = -1; float v2 = -3.0e38f;
    for (int e = 0; e < EE; ++e) { if (e == i1) continue; float v = l[e]; if (v > v2) { v2 = v; i2 = e; } }
    float g1 = 1.f / (1.f + expf(v2 - v1));
    float g2 = 1.f - g1;
    te[2 * t] = i1; te[2 * t + 1] = i2;
    tg[2 * t] = g1; tg[2 * t + 1] = g2;
    atomicAdd(&lcnt[i1], 1); atomicAdd(&lcnt[i2], 1);
  }
  __syncthreads();
  if (threadIdx.x < EE) atomicAdd(&cnt[threadIdx.x], lcnt[threadIdx.x]);
}

__global__ void zero_k(int* cnt, int* cursor) {
  if (threadIdx.x < EE) { cnt[threadIdx.x] = 0; cursor[threadIdx.x] = 0; }
}
__global__ void prefix_k(const int* __restrict__ cnt, int* __restrict__ offs) {
  if (threadIdx.x == 0) { int a = 0; for (int e = 0; e < EE; ++e) { offs[e] = a; a += cnt[e]; } }
}

// slot assignment + inverse map (tokmap[slot] = token) for fused-gather GEMM
__global__ __launch_bounds__(256) void slot_k(const int* __restrict__ te, const int* __restrict__ offs,
                                              int* cursor, int* __restrict__ slot, int* __restrict__ tokmap) {
  __shared__ int lcnt[EE];
  __shared__ int lbase[EE];
  if (threadIdx.x < EE) lcnt[threadIdx.x] = 0;
  __syncthreads();
  int a = blockIdx.x * 256 + threadIdx.x;
  int e = 0, r = 0;
  bool ok = a < NASSIGN;
  if (ok) { e = te[a]; r = atomicAdd(&lcnt[e], 1); }
  __syncthreads();
  if (threadIdx.x < EE) lbase[threadIdx.x] = atomicAdd(&cursor[threadIdx.x], lcnt[threadIdx.x]);
  __syncthreads();
  if (ok) {
    int s = offs[e] + lbase[e] + r;
    slot[a] = s;
    tokmap[s] = a >> 1;
  }
}

__global__ __launch_bounds__(192) void combine_k(float* X, const unsigned short* __restrict__ EO,
                                                 const int* __restrict__ slot, const float* __restrict__ tg) {
  int t = blockIdx.x;
  int s0 = slot[2 * t], s1 = slot[2 * t + 1];
  float g0 = tg[2 * t], g1 = tg[2 * t + 1];
  float4* x = (float4*)(X + (size_t)t * DD);
  uint2 a = *(const uint2*)(EO + (size_t)s0 * DD + threadIdx.x * 4);
  uint2 b = *(const uint2*)(EO + (size_t)s1 * DD + threadIdx.x * 4);
  float4 xv = x[threadIdx.x];
  xv.x += g0 * bf2f((unsigned short)(a.x & 0xFFFF)) + g1 * bf2f((unsigned short)(b.x & 0xFFFF));
  xv.y += g0 * bf2f((unsigned short)(a.x >> 16))    + g1 * bf2f((unsigned short)(b.x >> 16));
  xv.z += g0 * bf2f((unsigned short)(a.y & 0xFFFF)) + g1 * bf2f((unsigned short)(b.y & 0xFFFF));
  xv.w += g0 * bf2f((unsigned short)(a.y >> 16))    + g1 * bf2f((unsigned short)(b.y >> 16));
  x[threadIdx.x] = xv;
}

// ---------------- prologue / epilogue ----------------
__global__ void addpos_k(const float* __restrict__ x0, const float* __restrict__ x1,
                         const float* __restrict__ pos, float* __restrict__ X) {
  size_t i = (size_t)blockIdx.x * 256 + threadIdx.x;
  if (i >= (size_t)NTOK * DD) return;
  int d = (int)(i % DD); size_t row = i / DD;
  int s = (int)(row % SS); int b = (int)(row / SS);
  float v = (s < PP) ? x0[((size_t)b * PP + s) * DD + d] : x1[((size_t)b * PP + (s - PP)) * DD + d];
  X[i] = v + pos[(size_t)s * DD + d];
}

__global__ __launch_bounds__(256) void pool_k(const float* __restrict__ X, float* __restrict__ pooled) {
  int b = blockIdx.x, half = blockIdx.y;
  int tid = threadIdx.x;
  for (int d = tid; d < DD; d += 256) {
    float s = 0.f;
    for (int p = 0; p < PP; ++p) s += X[((size_t)(b * SS) + half * PP + p) * DD + d];
    pooled[(size_t)b * (2 * DD) + half * DD + d] = s * (1.f / PP);
  }
}

__global__ __launch_bounds__(256) void head1a_k(const float* __restrict__ pooled, const float* __restrict__ w1,
                                                float* __restrict__ part) {
  int n0 = blockIdx.x * 64, k0 = blockIdx.y * 96;
  __shared__ float w1s[96][64];
  __shared__ float ps[32][97];
  int tid = threadIdx.x;
  for (int i = tid; i < 96 * 64; i += 256) { int k = i >> 6, c = i & 63; w1s[k][c] = w1[(size_t)(k0 + k) * DD + n0 + c]; }
  for (int i = tid; i < 32 * 96; i += 256) { int b = i / 96, k = i - b * 96; ps[b][k] = pooled[(size_t)b * (2 * DD) + k0 + k]; }
  __syncthreads();
  int b = tid & 31, cg = tid >> 5;
  float acc[8] = {};
  for (int k = 0; k < 96; ++k) {
    float pb = ps[b][k];
#pragma unroll
    for (int c = 0; c < 8; ++c) acc[c] = fmaf(pb, w1s[k][cg * 8 + c], acc[c]);
  }
  float* dst = part + ((size_t)blockIdx.y * 32 + b) * DD + n0 + cg * 8;
#pragma unroll
  for (int c = 0; c < 8; ++c) dst[c] = acc[c];
}

__global__ __launch_bounds__(256) void head1b_k(const float* __restrict__ part, const float* __restrict__ b1,
                                                float* __restrict__ h1) {
  int idx = blockIdx.x * 256 + threadIdx.x;
  float s = b1[idx % DD];
  for (int r = 0; r < 16; ++r) s += part[(size_t)r * 32 * DD + idx];
  h1[idx] = fmaxf(s, 0.f);
}

__global__ __launch_bounds__(128) void head2_k(const float* __restrict__ h1, const float* __restrict__ w2,
                                               const float* __restrict__ b2, float* __restrict__ out) {
  int b = blockIdx.x;
  int c = threadIdx.x >> 6, lane = threadIdx.x & 63;
  float s = 0.f;
  for (int j = lane; j < DD; j += 64) s = fmaf(h1[(size_t)b * DD + j], w2[(size_t)j * 2 + c], s);
  for (int off = 32; off > 0; off >>= 1) s += __shfl_down(s, off, 64);
  if (lane == 0) out[b * 2 + c] = s + b2[c];
}

extern "C" void kernel_launch(void* const* d_in, const int* in_sizes, int n_in,
                              void* d_out, int out_size, void* d_ws, size_t ws_size,
                              hipStream_t stream) {
  const float* x0   = (const float*)d_in[0];
  const float* x1   = (const float*)d_in[1];
  const float* pos  = (const float*)d_in[2];
  const float* ln1w = (const float*)d_in[3];
  const float* ln1b = (const float*)d_in[4];
  const float* ln2w = (const float*)d_in[5];
  const float* ln2b = (const float*)d_in[6];
  const float* wq   = (const float*)d_in[7];
  const float* wkv  = (const float*)d_in[8];
  const float* wo   = (const float*)d_in[9];
  const float* bo   = (const float*)d_in[10];
  const float* moe_wg = (const float*)d_in[11];
  const float* moe_w1 = (const float*)d_in[12];
  const float* moe_b1 = (const float*)d_in[13];
  const float* moe_w2 = (const float*)d_in[14];
  const float* moe_b2 = (const float*)d_in[15];
  const float* mlp_w1 = (const float*)d_in[16];
  const float* mlp_b1 = (const float*)d_in[17];
  const float* mlp_w2 = (const float*)d_in[18];
  const float* mlp_b2 = (const float*)d_in[19];
  const float* head_w1 = (const float*)d_in[20];
  const float* head_b1 = (const float*)d_in[21];
  const float* head_w2 = (const float*)d_in[22];
  const float* head_b2 = (const float*)d_in[23];
  float* out = (float*)d_out;
  (void)in_sizes; (void)n_in; (void)out_size; (void)ws_size;

  char* w = (char*)d_ws;
  float* X = (float*)w;                 w += (size_t)NTOK * DD * 4;
  float* Y = (float*)w;                 w += (size_t)NTOK * DD * 4;
  unsigned short* Yb = (unsigned short*)w; w += (size_t)NTOK * DD * 2;
  unsigned short* WS = (unsigned short*)w; w += (size_t)18874368 * 2;   // per-layer weight scratch (bf16)
  char* U = w;                          w += (size_t)50331648;          // attn/moe union scratch
  float* logits = (float*)w;            w += (size_t)NTOK * EE * 4;
  float* tg = (float*)w;                w += (size_t)NASSIGN * 4;
  float* pooled = (float*)w;            w += (size_t)BB * 2 * DD * 4;
  float* h1 = (float*)w;                w += (size_t)BB * DD * 4;
  float* part = (float*)w;              w += (size_t)16 * BB * DD * 4;
  int* te = (int*)w;                    w += (size_t)NASSIGN * 4;
  int* slotb = (int*)w;                 w += (size_t)NASSIGN * 4;
  int* tokmap = (int*)w;                w += (size_t)NASSIGN * 4;
  int* cnt = (int*)w;                   w += 64;
  int* offs = (int*)w;                  w += 64;
  int* cursor = (int*)w;                w += 64;

  // attn-phase layout inside U
  unsigned short* QKVb = (unsigned short*)U;                       // 4096*2304 bf16
  unsigned short* AOb = (unsigned short*)(U + 35651584);           // 4096*768 bf16
  // moe-phase layout inside U (aliases attn buffers)
  unsigned short* Hid = (unsigned short*)(U + 12582912);           // 8192*1536 bf16
  unsigned short* EO  = (unsigned short*)(U + 37748736);           // 8192*768 bf16
  // per-layer weight scratch
  unsigned short* wqT  = WS;                 // 768*768   (rows 0..767 of combined QKV weight)
  unsigned short* wkvT = WS + 589824;        // 1536*768  (rows 768..2303)
  unsigned short* woT  = WS + 1769472;       // 768*768
  unsigned short* w1T  = WS;                 // ffn phase: up to 8*1536*768
  unsigned short* w2T  = WS + 9437184;       // up to 8*768*1536

  addpos_k<<<(NTOK * DD + 255) / 256, 256, 0, stream>>>(x0, x1, pos, X);

  for (int l = 0; l < LL; ++l) {
    tconv_k<<<dim3(24, 24), 256, 0, stream>>>(wq + (size_t)l * DD * DD, wqT, DD, DD);
    tconv_k<<<dim3(48, 24), 256, 0, stream>>>(wkv + (size_t)l * DD * 2 * DD, wkvT, DD, 2 * DD);
    tconv_k<<<dim3(24, 24), 256, 0, stream>>>(wo + (size_t)l * DD * DD, woT, DD, DD);
    ln_k<false><<<NTOK, 256, 0, stream>>>(X, Y, Yb, ln1w + l * DD, ln1b + l * DD);
    // fused QKV = Yb @ [wq|wkv]^T  (N=2304), M-affinity 1D grid
    mgemm_k<5><<<18 * 64, 256, 0, stream>>>(Yb, wqT, nullptr, (void*)QKVb, nullptr, NTOK, QKVN, DD);
    attn_fused_k<<<BB * HH, 256, 0, stream>>>(QKVb, AOb);
    mgemm_k<1><<<6 * 64, 256, 0, stream>>>(AOb, woT, bo + l * DD, (void*)X, nullptr, NTOK, DD, DD);
    if (l % 2 == 0) {
      int s = l / 2;
      ln_k<true><<<NTOK, 256, 0, stream>>>(X, Y, Yb, ln2w + l * DD, ln2b + l * DD);
      tconv_k<<<dim3(48, 24, 8), 256, 0, stream>>>(moe_w1 + (size_t)s * EE * DD * 2 * DD, w1T, DD, 2 * DD);
      tconv_k<<<dim3(24, 48, 8), 256, 0, stream>>>(moe_w2 + (size_t)s * EE * 2 * DD * DD, w2T, 2 * DD, DD);
      zero_k<<<1, 64, 0, stream>>>(cnt, cursor);
      gate_logits_k<<<NTOK, 256, 0, stream>>>(Y, moe_wg + (size_t)s * DD * EE, logits);
      topk_k<<<NTOK / 256, 256, 0, stream>>>(logits, te, tg, cnt);
      prefix_k<<<1, 1, 0, stream>>>(cnt, offs);
      slot_k<<<NASSIGN / 256, 256, 0, stream>>>(te, offs, cursor, slotb, tokmap);
      // up-proj: 64x256 tile, fused gather via tokmap
      megemmA_k<<<dim3(6, 128, 8), 256, 0, stream>>>(Yb, tokmap, w1T, moe_b1 + (size_t)s * EE * 2 * DD,
                                                     Hid, offs, cnt, 2 * DD, DD);
      megemm_k<4><<<dim3(6, 128, 8), 256, 0, stream>>>(Hid, w2T, moe_b2 + (size_t)s * EE * DD, EO, offs, cnt, DD, 2 * DD);
      combine_k<<<NTOK, 192, 0, stream>>>(X, EO, slotb, tg);
    } else {
      int m = l / 2;
      ln_k<false><<<NTOK, 256, 0, stream>>>(X, Y, Yb, ln2w + l * DD, ln2b + l * DD);
      tconv_k<<<dim3(48, 24), 256, 0, stream>>>(mlp_w1 + (size_t)m * DD * 2 * DD, w1T, DD, 2 * DD);
      tconv_k<<<dim3(24, 48), 256, 0, stream>>>(mlp_w2 + (size_t)m * 2 * DD * DD, w2T, 2 * DD, DD);
      mgemm_k<2><<<12 * 64, 256, 0, stream>>>(Yb, w1T, mlp_b1 + (size_t)m * 2 * DD, (void*)Hid, nullptr, NTOK, 2 * DD, DD);
      mgemm_k<3><<<6 * 64, 256, 0, stream>>>(Hid, w2T, mlp_b2 + (size_t)m * DD, (void*)X, X, NTOK, DD, 2 * DD);
    }
  }

  pool_k<<<dim3(BB, 2), 256, 0, stream>>>(X, pooled);
  head1a_k<<<dim3(12, 16), 256, 0, stream>>>(pooled, head_w1, part);
  head1b_k<<<96, 256, 0, stream>>>(part, head_b1, h1);
  head2_k<<<BB, 128, 0, stream>>>(h1, head_w2, head_b2, out);
}

// Round 14
// 824.578 us; speedup vs baseline: 1.0567x; 1.0567x over previous
//
#include <hip/hip_runtime.h>
#include <math.h>

#define BB 32
#define PP 64
#define SS 128
#define DD 768
#define HH 8
#define HD 96
#define EE 8
#define LL 4
#define NTOK 4096
#define NASSIGN 8192
#define QKVN 2304

typedef __attribute__((ext_vector_type(8))) short bf16x8;
typedef __attribute__((ext_vector_type(4))) float f32x4;

__device__ __forceinline__ float bf2f(unsigned short u) {
  union { unsigned int i; float f; } v; v.i = ((unsigned int)u) << 16; return v.f;
}
__device__ __forceinline__ unsigned short f2bf(float f) {
  union { float f; unsigned int u; } v; v.f = f;
  unsigned int r = v.u + 0x7FFFu + ((v.u >> 16) & 1u);
  return (unsigned short)(r >> 16);
}
__device__ __forceinline__ void gload16(const void* g, void* l) {
  __builtin_amdgcn_global_load_lds((const __attribute__((address_space(1))) unsigned int*)g,
                                   (__attribute__((address_space(3))) unsigned int*)l, 16, 0, 0);
}

// ---------------- weight transpose + bf16 convert: W[K][N] f32 -> WT[N][K] bf16 ----------------
__global__ __launch_bounds__(256) void tconv_k(const float* __restrict__ W, unsigned short* __restrict__ WT,
                                               int K, int N) {
  const float* Wb = W + (size_t)blockIdx.z * K * N;
  unsigned short* WTb = WT + (size_t)blockIdx.z * K * N;
  __shared__ float t[32][33];
  int tx = threadIdx.x & 31, ty = threadIdx.x >> 5;
  int n0 = blockIdx.x * 32, k0 = blockIdx.y * 32;
#pragma unroll
  for (int r = 0; r < 4; ++r) t[ty * 4 + r][tx] = Wb[(size_t)(k0 + ty * 4 + r) * N + n0 + tx];
  __syncthreads();
#pragma unroll
  for (int r = 0; r < 4; ++r) WTb[(size_t)(n0 + ty * 4 + r) * K + k0 + tx] = f2bf(t[tx][ty * 4 + r]);
}

// ---------------- LayerNorm: X f32 -> (Y f32 optional) + Yb bf16 ----------------
template <bool WRITEY>
__global__ __launch_bounds__(256) void ln_k(const float* __restrict__ X, float* __restrict__ Y,
                                            unsigned short* __restrict__ Yb,
                                            const float* __restrict__ w, const float* __restrict__ b) {
  int r = blockIdx.x; int tid = threadIdx.x;
  const float* x = X + (size_t)r * DD;
  float v0 = x[tid], v1 = x[tid + 256], v2 = x[tid + 512];
  __shared__ float rs[256], rss[256];
  rs[tid] = v0 + v1 + v2;
  rss[tid] = v0 * v0 + v1 * v1 + v2 * v2;
  __syncthreads();
  for (int off = 128; off > 0; off >>= 1) {
    if (tid < off) { rs[tid] += rs[tid + off]; rss[tid] += rss[tid + off]; }
    __syncthreads();
  }
  float mean = rs[0] * (1.f / DD);
  float var = rss[0] * (1.f / DD) - mean * mean;
  float rstd = rsqrtf(var + 1e-5f);
  unsigned short* yb = Yb + (size_t)r * DD;
  float o0 = (v0 - mean) * rstd * w[tid] + b[tid];
  float o1 = (v1 - mean) * rstd * w[tid + 256] + b[tid + 256];
  float o2 = (v2 - mean) * rstd * w[tid + 512] + b[tid + 512];
  if (WRITEY) {
    float* y = Y + (size_t)r * DD;
    y[tid] = o0; y[tid + 256] = o1; y[tid + 512] = o2;
  }
  yb[tid] = f2bf(o0); yb[tid + 256] = f2bf(o1); yb[tid + 512] = f2bf(o2);
}

// ---------------- MFMA GEMM, 64x128 tile, BK=64, swizzled LDS, XCD M-affinity remap ----------------
// 1D grid of (M/64)*(N/128) blocks; M/64 must be divisible by 8.
// EPI 1: f32 2*(v+bias)   2: bf16 gelu(v+bias)   3: f32 res+v+bias   5: bf16 v
template <int EPI>
__global__ __launch_bounds__(256) void mgemm_k(const unsigned short* __restrict__ A,
                                               const unsigned short* __restrict__ WT,
                                               const float* __restrict__ bias, void* __restrict__ Cv,
                                               const float* res, int M, int N, int K) {
  __shared__ short As[64 * 64];
  __shared__ short Bs[128 * 64];
  int tid = threadIdx.x;
  int wv = tid >> 6, ln = tid & 63;
  int NT = N >> 7;
  int bid = blockIdx.x;
  int xcd = bid & 7, k = bid >> 3;
  int m0 = ((k / NT) * 8 + xcd) * 64;
  int n0 = (k % NT) * 128;
  f32x4 acc[2][4] = {};
  int lr = ln & 15, kc = ln >> 4;
  int wr = wv >> 1, wc = wv & 1;
  int srow = ln >> 3;
  int scol = ((ln & 7) ^ srow) * 8;
  for (int k0 = 0; k0 < K; k0 += 64) {
#pragma unroll
    for (int i = 0; i < 2; ++i) {
      int ch = wv * 2 + i;
      gload16(A + (size_t)(m0 + ch * 8 + srow) * K + k0 + scol, &As[ch * 512]);
    }
#pragma unroll
    for (int c = 0; c < 4; ++c) {
      int ch = wv * 4 + c;
      gload16(WT + (size_t)(n0 + ch * 8 + srow) * K + k0 + scol, &Bs[ch * 512]);
    }
    __syncthreads();
#pragma unroll
    for (int ks = 0; ks < 2; ++ks) {
      int sl = ((ks * 4 + kc) ^ (lr & 7)) * 8;
      bf16x8 af[2], bfr[4];
#pragma unroll
      for (int i = 0; i < 2; ++i) af[i] = *(const bf16x8*)&As[(wr * 32 + i * 16 + lr) * 64 + sl];
#pragma unroll
      for (int j = 0; j < 4; ++j) bfr[j] = *(const bf16x8*)&Bs[(wc * 64 + j * 16 + lr) * 64 + sl];
#pragma unroll
      for (int i = 0; i < 2; ++i)
#pragma unroll
        for (int j = 0; j < 4; ++j)
          acc[i][j] = __builtin_amdgcn_mfma_f32_16x16x32_bf16(af[i], bfr[j], acc[i][j], 0, 0, 0);
    }
    __syncthreads();
  }
  int lg = ln >> 4;
#pragma unroll
  for (int i = 0; i < 2; ++i)
#pragma unroll
    for (int j = 0; j < 4; ++j)
#pragma unroll
      for (int r = 0; r < 4; ++r) {
        int m = m0 + wr * 32 + i * 16 + lg * 4 + r;
        int n = n0 + wc * 64 + j * 16 + lr;
        float v = acc[i][j][r];
        if constexpr (EPI == 1) { ((float*)Cv)[(size_t)m * N + n] = 2.f * (v + bias[n]); }
        else if constexpr (EPI == 2) { v += bias[n]; v = 0.5f * v * (1.f + erff(v * 0.70710678118f)); ((unsigned short*)Cv)[(size_t)m * N + n] = f2bf(v); }
        else if constexpr (EPI == 3) { ((float*)Cv)[(size_t)m * N + n] = res[(size_t)m * N + n] + v + bias[n]; }
        else { ((unsigned short*)Cv)[(size_t)m * N + n] = f2bf(v); }
      }
}

// ---------------- grouped expert MFMA GEMM, 64x128 tile, expert->XCD affinity ----------------
// grid = (8 experts, NT, MT): blockIdx.x = expert = XCD -> expert weights + tokens stay in one L2.
// EPI 2: bf16 gelu(v+bias)   4: bf16 v+bias
template <int EPI>
__global__ __launch_bounds__(256) void megemm_k(const unsigned short* __restrict__ Aall,
                                                const unsigned short* __restrict__ WTall,
                                                const float* __restrict__ Ball, unsigned short* __restrict__ C,
                                                const int* __restrict__ offs, const int* __restrict__ cntp,
                                                int N, int K) {
  int e = blockIdx.x;
  int cnt = cntp[e];
  int mt = blockIdx.z;
  if (mt * 64 >= cnt) return;
  int valid = cnt - mt * 64; if (valid > 64) valid = 64;
  const unsigned short* A = Aall + (size_t)(offs[e] + mt * 64) * K;
  const unsigned short* WT = WTall + (size_t)e * K * N;
  const float* Bv = Ball + (size_t)e * N;
  unsigned short* Ce = C + (size_t)(offs[e] + mt * 64) * N;
  __shared__ short As[64 * 64];
  __shared__ short Bs[128 * 64];
  int tid = threadIdx.x;
  int wv = tid >> 6, ln = tid & 63;
  int n0 = blockIdx.y * 128;
  f32x4 acc[2][4] = {};
  int lr = ln & 15, kc = ln >> 4;
  int wr = wv >> 1, wc = wv & 1;
  int srow = ln >> 3;
  int scol = ((ln & 7) ^ srow) * 8;
  for (int k0 = 0; k0 < K; k0 += 64) {
#pragma unroll
    for (int i = 0; i < 2; ++i) {
      int ch = wv * 2 + i;
      gload16(A + (size_t)(ch * 8 + srow) * K + k0 + scol, &As[ch * 512]);
    }
#pragma unroll
    for (int c = 0; c < 4; ++c) {
      int ch = wv * 4 + c;
      gload16(WT + (size_t)(n0 + ch * 8 + srow) * K + k0 + scol, &Bs[ch * 512]);
    }
    __syncthreads();
#pragma unroll
    for (int ks = 0; ks < 2; ++ks) {
      int sl = ((ks * 4 + kc) ^ (lr & 7)) * 8;
      bf16x8 af[2], bfr[4];
#pragma unroll
      for (int i = 0; i < 2; ++i) af[i] = *(const bf16x8*)&As[(wr * 32 + i * 16 + lr) * 64 + sl];
#pragma unroll
      for (int j = 0; j < 4; ++j) bfr[j] = *(const bf16x8*)&Bs[(wc * 64 + j * 16 + lr) * 64 + sl];
#pragma unroll
      for (int i = 0; i < 2; ++i)
#pragma unroll
        for (int j = 0; j < 4; ++j)
          acc[i][j] = __builtin_amdgcn_mfma_f32_16x16x32_bf16(af[i], bfr[j], acc[i][j], 0, 0, 0);
    }
    __syncthreads();
  }
  int lg = ln >> 4;
#pragma unroll
  for (int i = 0; i < 2; ++i)
#pragma unroll
    for (int j = 0; j < 4; ++j)
#pragma unroll
      for (int r = 0; r < 4; ++r) {
        int ml = wr * 32 + i * 16 + lg * 4 + r;
        if (ml >= valid) continue;
        int n = n0 + wc * 64 + j * 16 + lr;
        float v = acc[i][j][r] + Bv[n];
        if constexpr (EPI == 2) { v = 0.5f * v * (1.f + erff(v * 0.70710678118f)); }
        Ce[(size_t)ml * N + n] = f2bf(v);
      }
}

// ---------------- fused attention: one WG per (b,h), reads combined QKV (stride 2304) ----------------
__global__ __launch_bounds__(256) void attn_fused_k(const unsigned short* __restrict__ QKV,
                                                    unsigned short* __restrict__ AOb) {
  __shared__ short lds[57088];
  const int QS = 0, KS = 13312, VT = 26624, PS = 39680;
  int tid = threadIdx.x;
  int b = blockIdx.x >> 3, h = blockIdx.x & 7;
  const size_t qbase = (size_t)(b * SS) * QKVN + h * HD;
  for (int c = tid; c < 1536; c += 256) {
    int row = c / 12, col8 = c % 12;
    uint4 v = *(const uint4*)(QKV + qbase + (size_t)row * QKVN + col8 * 8);
    *(uint4*)&lds[QS + row * 104 + col8 * 8] = v;
  }
  const size_t kbase = qbase + DD;
  for (int c = tid; c < 1536; c += 256) {
    int row = c / 12, col8 = c % 12;
    uint4 v = *(const uint4*)(QKV + kbase + (size_t)row * QKVN + col8 * 8);
    *(uint4*)&lds[KS + row * 104 + col8 * 8] = v;
  }
  const size_t vbase = qbase + 2 * DD;
  for (int c = tid; c < 6144; c += 256) {
    int j = c / 48, dp = c % 48;
    unsigned int u = *(const unsigned int*)(QKV + vbase + (size_t)j * QKVN + dp * 2);
    lds[VT + (2 * dp) * 136 + j] = (short)(u & 0xFFFF);
    lds[VT + (2 * dp + 1) * 136 + j] = (short)(u >> 16);
  }
  __syncthreads();

  int w = tid >> 6, ln = tid & 63;
  int lr = ln & 15, kc = ln >> 4;
  f32x4 acc[2][8] = {};
#pragma unroll
  for (int kk = 0; kk < 3; ++kk) {
    bf16x8 af[2], bfv[8];
#pragma unroll
    for (int i = 0; i < 2; ++i)
      af[i] = *(const bf16x8*)&lds[QS + (32 * w + i * 16 + lr) * 104 + kk * 32 + kc * 8];
#pragma unroll
    for (int j = 0; j < 8; ++j)
      bfv[j] = *(const bf16x8*)&lds[KS + (j * 16 + lr) * 104 + kk * 32 + kc * 8];
#pragma unroll
    for (int i = 0; i < 2; ++i)
#pragma unroll
      for (int j = 0; j < 8; ++j)
        acc[i][j] = __builtin_amdgcn_mfma_f32_16x16x32_bf16(af[i], bfv[j], acc[i][j], 0, 0, 0);
  }
  const float c1 = 0.10206207261596577f * 1.4426950408889634f;
  float inv_[2][4];
#pragma unroll
  for (int i = 0; i < 2; ++i)
#pragma unroll
    for (int r = 0; r < 4; ++r) {
      float m = acc[i][0][r];
#pragma unroll
      for (int j = 1; j < 8; ++j) m = fmaxf(m, acc[i][j][r]);
      m = fmaxf(m, __shfl_xor(m, 1, 64)); m = fmaxf(m, __shfl_xor(m, 2, 64));
      m = fmaxf(m, __shfl_xor(m, 4, 64)); m = fmaxf(m, __shfl_xor(m, 8, 64));
      float p[8]; float s = 0.f;
#pragma unroll
      for (int j = 0; j < 8; ++j) { p[j] = exp2f((acc[i][j][r] - m) * c1); s += p[j]; }
      s += __shfl_xor(s, 1, 64); s += __shfl_xor(s, 2, 64);
      s += __shfl_xor(s, 4, 64); s += __shfl_xor(s, 8, 64);
      inv_[i][r] = 1.f / s;
      short* pw = &lds[PS + w * 4352 + (i * 16 + kc * 4 + r) * 136 + lr];
#pragma unroll
      for (int j = 0; j < 8; ++j) pw[j * 16] = (short)f2bf(p[j]);
    }
  f32x4 acc2[2][6] = {};
#pragma unroll
  for (int kk = 0; kk < 4; ++kk) {
    bf16x8 pa[2], vb[6];
#pragma unroll
    for (int i = 0; i < 2; ++i)
      pa[i] = *(const bf16x8*)&lds[PS + w * 4352 + (i * 16 + lr) * 136 + kk * 32 + kc * 8];
#pragma unroll
    for (int j = 0; j < 6; ++j)
      vb[j] = *(const bf16x8*)&lds[VT + (j * 16 + lr) * 136 + kk * 32 + kc * 8];
#pragma unroll
    for (int i = 0; i < 2; ++i)
#pragma unroll
      for (int j = 0; j < 6; ++j)
        acc2[i][j] = __builtin_amdgcn_mfma_f32_16x16x32_bf16(pa[i], vb[j], acc2[i][j], 0, 0, 0);
  }
#pragma unroll
  for (int i = 0; i < 2; ++i)
#pragma unroll
    for (int j = 0; j < 6; ++j)
#pragma unroll
      for (int r = 0; r < 4; ++r) {
        int row = 32 * w + i * 16 + kc * 4 + r;
        AOb[((size_t)b * SS + row) * DD + h * HD + j * 16 + lr] = f2bf(acc2[i][j][r] * inv_[i][r]);
      }
}

// ---------------- MoE gating ----------------
__global__ __launch_bounds__(256) void gate_logits_k(const float* __restrict__ Y, const float* __restrict__ wg,
                                                     float* __restrict__ logits) {
  int t = blockIdx.x; int tid = threadIdx.x;
  int e = tid >> 5, lane = tid & 31;
  const float* y = Y + (size_t)t * DD;
  float s = 0.f;
  for (int d = lane; d < DD; d += 32) s = fmaf(y[d], wg[(size_t)d * EE + e], s);
  for (int off = 16; off > 0; off >>= 1) s += __shfl_down(s, off, 32);
  if (lane == 0) logits[(size_t)t * EE + e] = s;
}

__global__ __launch_bounds__(256) void topk_k(const float* __restrict__ logits, int* __restrict__ te,
                                              float* __restrict__ tg, int* __restrict__ cnt) {
  __shared__ int lcnt[EE];
  if (threadIdx.x < EE) lcnt[threadIdx.x] = 0;
  __syncthreads();
  int t = blockIdx.x * 256 + threadIdx.x;
  if (t < NTOK) {
    const float* l = logits + (size_t)t * EE;
    int i1 = 0; float v1 = l[0];
    for (int e = 1; e < EE; ++e) { float v = l[e]; if (v > v1) { v1 = v; i1 = e; } }
    int i2 = -1; float v2 = -3.0e38f;
    for (int e = 0; e < EE; ++e) { if (e == i1) continue; float v = l[e]; if (v > v2) { v2 = v; i2 = e; } }
    float g1 = 1.f / (1.f + expf(v2 - v1));
    float g2 = 1.f - g1;
    te[2 * t] = i1; te[2 * t + 1] = i2;
    tg[2 * t] = g1; tg[2 * t + 1] = g2;
    atomicAdd(&lcnt[i1], 1); atomicAdd(&lcnt[i2], 1);
  }
  __syncthreads();
  if (threadIdx.x < EE) atomicAdd(&cnt[threadIdx.x], lcnt[threadIdx.x]);
}

__global__ void zero_k(int* cnt, int* cursor) {
  if (threadIdx.x < EE) { cnt[threadIdx.x] = 0; cursor[threadIdx.x] = 0; }
}
__global__ void prefix_k(const int* __restrict__ cnt, int* __restrict__ offs) {
  if (threadIdx.x == 0) { int a = 0; for (int e = 0; e < EE; ++e) { offs[e] = a; a += cnt[e]; } }
}

__global__ __launch_bounds__(256) void slot_k(const int* __restrict__ te, const int* __restrict__ offs,
                                              int* cursor, int* __restrict__ slot) {
  __shared__ int lcnt[EE];
  __shared__ int lbase[EE];
  if (threadIdx.x < EE) lcnt[threadIdx.x] = 0;
  __syncthreads();
  int a = blockIdx.x * 256 + threadIdx.x;
  int e = 0, r = 0;
  bool ok = a < NASSIGN;
  if (ok) { e = te[a]; r = atomicAdd(&lcnt[e], 1); }
  __syncthreads();
  if (threadIdx.x < EE) lbase[threadIdx.x] = atomicAdd(&cursor[threadIdx.x], lcnt[threadIdx.x]);
  __syncthreads();
  if (ok) slot[a] = offs[e] + lbase[e] + r;
}

__global__ __launch_bounds__(192) void gather_k(const unsigned short* __restrict__ Yb, const int* __restrict__ slot,
                                                unsigned short* __restrict__ G) {
  int a = blockIdx.x; int t = a >> 1;
  int s = slot[a];
  const uint2* src = (const uint2*)(Yb + (size_t)t * DD);
  uint2* dst = (uint2*)(G + (size_t)s * DD);
  dst[threadIdx.x] = src[threadIdx.x];
}

__global__ __launch_bounds__(192) void combine_k(float* X, const unsigned short* __restrict__ EO,
                                                 const int* __restrict__ slot, const float* __restrict__ tg) {
  int t = blockIdx.x;
  int s0 = slot[2 * t], s1 = slot[2 * t + 1];
  float g0 = tg[2 * t], g1 = tg[2 * t + 1];
  float4* x = (float4*)(X + (size_t)t * DD);
  uint2 a = *(const uint2*)(EO + (size_t)s0 * DD + threadIdx.x * 4);
  uint2 b = *(const uint2*)(EO + (size_t)s1 * DD + threadIdx.x * 4);
  float4 xv = x[threadIdx.x];
  xv.x += g0 * bf2f((unsigned short)(a.x & 0xFFFF)) + g1 * bf2f((unsigned short)(b.x & 0xFFFF));
  xv.y += g0 * bf2f((unsigned short)(a.x >> 16))    + g1 * bf2f((unsigned short)(b.x >> 16));
  xv.z += g0 * bf2f((unsigned short)(a.y & 0xFFFF)) + g1 * bf2f((unsigned short)(b.y & 0xFFFF));
  xv.w += g0 * bf2f((unsigned short)(a.y >> 16))    + g1 * bf2f((unsigned short)(b.y >> 16));
  x[threadIdx.x] = xv;
}

// ---------------- prologue / epilogue ----------------
__global__ void addpos_k(const float* __restrict__ x0, const float* __restrict__ x1,
                         const float* __restrict__ pos, float* __restrict__ X) {
  size_t i = (size_t)blockIdx.x * 256 + threadIdx.x;
  if (i >= (size_t)NTOK * DD) return;
  int d = (int)(i % DD); size_t row = i / DD;
  int s = (int)(row % SS); int b = (int)(row / SS);
  float v = (s < PP) ? x0[((size_t)b * PP + s) * DD + d] : x1[((size_t)b * PP + (s - PP)) * DD + d];
  X[i] = v + pos[(size_t)s * DD + d];
}

__global__ __launch_bounds__(256) void pool_k(const float* __restrict__ X, float* __restrict__ pooled) {
  int b = blockIdx.x, half = blockIdx.y;
  int tid = threadIdx.x;
  for (int d = tid; d < DD; d += 256) {
    float s = 0.f;
    for (int p = 0; p < PP; ++p) s += X[((size_t)(b * SS) + half * PP + p) * DD + d];
    pooled[(size_t)b * (2 * DD) + half * DD + d] = s * (1.f / PP);
  }
}

__global__ __launch_bounds__(256) void head1a_k(const float* __restrict__ pooled, const float* __restrict__ w1,
                                                float* __restrict__ part) {
  int n0 = blockIdx.x * 64, k0 = blockIdx.y * 96;
  __shared__ float w1s[96][64];
  __shared__ float ps[32][97];
  int tid = threadIdx.x;
  for (int i = tid; i < 96 * 64; i += 256) { int k = i >> 6, c = i & 63; w1s[k][c] = w1[(size_t)(k0 + k) * DD + n0 + c]; }
  for (int i = tid; i < 32 * 96; i += 256) { int b = i / 96, k = i - b * 96; ps[b][k] = pooled[(size_t)b * (2 * DD) + k0 + k]; }
  __syncthreads();
  int b = tid & 31, cg = tid >> 5;
  float acc[8] = {};
  for (int k = 0; k < 96; ++k) {
    float pb = ps[b][k];
#pragma unroll
    for (int c = 0; c < 8; ++c) acc[c] = fmaf(pb, w1s[k][cg * 8 + c], acc[c]);
  }
  float* dst = part + ((size_t)blockIdx.y * 32 + b) * DD + n0 + cg * 8;
#pragma unroll
  for (int c = 0; c < 8; ++c) dst[c] = acc[c];
}

__global__ __launch_bounds__(256) void head1b_k(const float* __restrict__ part, const float* __restrict__ b1,
                                                float* __restrict__ h1) {
  int idx = blockIdx.x * 256 + threadIdx.x;
  float s = b1[idx % DD];
  for (int r = 0; r < 16; ++r) s += part[(size_t)r * 32 * DD + idx];
  h1[idx] = fmaxf(s, 0.f);
}

__global__ __launch_bounds__(128) void head2_k(const float* __restrict__ h1, const float* __restrict__ w2,
                                               const float* __restrict__ b2, float* __restrict__ out) {
  int b = blockIdx.x;
  int c = threadIdx.x >> 6, lane = threadIdx.x & 63;
  float s = 0.f;
  for (int j = lane; j < DD; j += 64) s = fmaf(h1[(size_t)b * DD + j], w2[(size_t)j * 2 + c], s);
  for (int off = 32; off > 0; off >>= 1) s += __shfl_down(s, off, 64);
  if (lane == 0) out[b * 2 + c] = s + b2[c];
}

extern "C" void kernel_launch(void* const* d_in, const int* in_sizes, int n_in,
                              void* d_out, int out_size, void* d_ws, size_t ws_size,
                              hipStream_t stream) {
  const float* x0   = (const float*)d_in[0];
  const float* x1   = (const float*)d_in[1];
  const float* pos  = (const float*)d_in[2];
  const float* ln1w = (const float*)d_in[3];
  const float* ln1b = (const float*)d_in[4];
  const float* ln2w = (const float*)d_in[5];
  const float* ln2b = (const float*)d_in[6];
  const float* wq   = (const float*)d_in[7];
  const float* wkv  = (const float*)d_in[8];
  const float* wo   = (const float*)d_in[9];
  const float* bo   = (const float*)d_in[10];
  const float* moe_wg = (const float*)d_in[11];
  const float* moe_w1 = (const float*)d_in[12];
  const float* moe_b1 = (const float*)d_in[13];
  const float* moe_w2 = (const float*)d_in[14];
  const float* moe_b2 = (const float*)d_in[15];
  const float* mlp_w1 = (const float*)d_in[16];
  const float* mlp_b1 = (const float*)d_in[17];
  const float* mlp_w2 = (const float*)d_in[18];
  const float* mlp_b2 = (const float*)d_in[19];
  const float* head_w1 = (const float*)d_in[20];
  const float* head_b1 = (const float*)d_in[21];
  const float* head_w2 = (const float*)d_in[22];
  const float* head_b2 = (const float*)d_in[23];
  float* out = (float*)d_out;
  (void)in_sizes; (void)n_in; (void)out_size; (void)ws_size;

  char* w = (char*)d_ws;
  float* X = (float*)w;                 w += (size_t)NTOK * DD * 4;
  float* Y = (float*)w;                 w += (size_t)NTOK * DD * 4;
  unsigned short* Yb = (unsigned short*)w; w += (size_t)NTOK * DD * 2;
  unsigned short* WS = (unsigned short*)w; w += (size_t)18874368 * 2;   // per-layer weight scratch (bf16)
  char* U = w;                          w += (size_t)50331648;          // attn/moe union scratch
  float* logits = (float*)w;            w += (size_t)NTOK * EE * 4;
  float* tg = (float*)w;                w += (size_t)NASSIGN * 4;
  float* pooled = (float*)w;            w += (size_t)BB * 2 * DD * 4;
  float* h1 = (float*)w;                w += (size_t)BB * DD * 4;
  float* part = (float*)w;              w += (size_t)16 * BB * DD * 4;
  int* te = (int*)w;                    w += (size_t)NASSIGN * 4;
  int* slotb = (int*)w;                 w += (size_t)NASSIGN * 4;
  int* cnt = (int*)w;                   w += 64;
  int* offs = (int*)w;                  w += 64;
  int* cursor = (int*)w;                w += 64;

  // attn-phase layout inside U
  unsigned short* QKVb = (unsigned short*)U;                       // 4096*2304 bf16
  unsigned short* AOb = (unsigned short*)(U + 35651584);           // 4096*768 bf16
  // moe-phase layout inside U (aliases attn buffers)
  unsigned short* G   = (unsigned short*)U;                        // 8192*768 bf16
  unsigned short* Hid = (unsigned short*)(U + 12582912);           // 8192*1536 bf16
  unsigned short* EO  = (unsigned short*)(U + 37748736);           // 8192*768 bf16
  // per-layer weight scratch
  unsigned short* wqT  = WS;                 // 768*768   (rows 0..767 of combined QKV weight)
  unsigned short* wkvT = WS + 589824;        // 1536*768  (rows 768..2303)
  unsigned short* woT  = WS + 1769472;       // 768*768
  unsigned short* w1T  = WS;                 // ffn phase: up to 8*1536*768
  unsigned short* w2T  = WS + 9437184;       // up to 8*768*1536

  addpos_k<<<(NTOK * DD + 255) / 256, 256, 0, stream>>>(x0, x1, pos, X);

  for (int l = 0; l < LL; ++l) {
    tconv_k<<<dim3(24, 24), 256, 0, stream>>>(wq + (size_t)l * DD * DD, wqT, DD, DD);
    tconv_k<<<dim3(48, 24), 256, 0, stream>>>(wkv + (size_t)l * DD * 2 * DD, wkvT, DD, 2 * DD);
    tconv_k<<<dim3(24, 24), 256, 0, stream>>>(wo + (size_t)l * DD * DD, woT, DD, DD);
    ln_k<false><<<NTOK, 256, 0, stream>>>(X, Y, Yb, ln1w + l * DD, ln1b + l * DD);
    // fused QKV = Yb @ [wq|wkv]^T  (N=2304), M-affinity 1D grid
    mgemm_k<5><<<18 * 64, 256, 0, stream>>>(Yb, wqT, nullptr, (void*)QKVb, nullptr, NTOK, QKVN, DD);
    attn_fused_k<<<BB * HH, 256, 0, stream>>>(QKVb, AOb);
    mgemm_k<1><<<6 * 64, 256, 0, stream>>>(AOb, woT, bo + l * DD, (void*)X, nullptr, NTOK, DD, DD);
    if (l % 2 == 0) {
      int s = l / 2;
      ln_k<true><<<NTOK, 256, 0, stream>>>(X, Y, Yb, ln2w + l * DD, ln2b + l * DD);
      tconv_k<<<dim3(48, 24, 8), 256, 0, stream>>>(moe_w1 + (size_t)s * EE * DD * 2 * DD, w1T, DD, 2 * DD);
      tconv_k<<<dim3(24, 48, 8), 256, 0, stream>>>(moe_w2 + (size_t)s * EE * 2 * DD * DD, w2T, 2 * DD, DD);
      zero_k<<<1, 64, 0, stream>>>(cnt, cursor);
      gate_logits_k<<<NTOK, 256, 0, stream>>>(Y, moe_wg + (size_t)s * DD * EE, logits);
      topk_k<<<NTOK / 256, 256, 0, stream>>>(logits, te, tg, cnt);
      prefix_k<<<1, 1, 0, stream>>>(cnt, offs);
      slot_k<<<NASSIGN / 256, 256, 0, stream>>>(te, offs, cursor, slotb);
      gather_k<<<NASSIGN, 192, 0, stream>>>(Yb, slotb, G);
      // expert -> XCD affinity: blockIdx.x = expert
      megemm_k<2><<<dim3(8, 12, 128), 256, 0, stream>>>(G, w1T, moe_b1 + (size_t)s * EE * 2 * DD, Hid, offs, cnt, 2 * DD, DD);
      megemm_k<4><<<dim3(8, 6, 128), 256, 0, stream>>>(Hid, w2T, moe_b2 + (size_t)s * EE * DD, EO, offs, cnt, DD, 2 * DD);
      combine_k<<<NTOK, 192, 0, stream>>>(X, EO, slotb, tg);
    } else {
      int m = l / 2;
      ln_k<false><<<NTOK, 256, 0, stream>>>(X, Y, Yb, ln2w + l * DD, ln2b + l * DD);
      tconv_k<<<dim3(48, 24), 256, 0, stream>>>(mlp_w1 + (size_t)m * DD * 2 * DD, w1T, DD, 2 * DD);
      tconv_k<<<dim3(24, 48), 256, 0, stream>>>(mlp_w2 + (size_t)m * 2 * DD * DD, w2T, 2 * DD, DD);
      mgemm_k<2><<<12 * 64, 256, 0, stream>>>(Yb, w1T, mlp_b1 + (size_t)m * 2 * DD, (void*)Hid, nullptr, NTOK, 2 * DD, DD);
      mgemm_k<3><<<6 * 64, 256, 0, stream>>>(Hid, w2T, mlp_b2 + (size_t)m * DD, (void*)X, X, NTOK, DD, 2 * DD);
    }
  }

  pool_k<<<dim3(BB, 2), 256, 0, stream>>>(X, pooled);
  head1a_k<<<dim3(12, 16), 256, 0, stream>>>(pooled, head_w1, part);
  head1b_k<<<96, 256, 0, stream>>>(part, head_b1, h1);
  head2_k<<<BB, 128, 0, stream>>>(h1, head_w2, head_b2, out);
}